// Round 6
// baseline (139.607 us; speedup 1.0000x reference)
//
#include <hip/hip_runtime.h>

// SNN forward: T=128, B=8192, I=2, H=256, O=2
//  cur[t,b,h] = x[t,b,0]*W1[h,0] + x[t,b,1]*W1[h,1]
//  scan: reset = (mem>1); mem = 0.9*mem + cur - reset; spk = (mem>1)
//  out[b,o] = (mean of spk over last 10 t) dot W2[o,:]
//
// R6 = R5 (lane=batch, coalesced float2 x loads, XCD-correct swizzle, depth-8
// register prefetch) with two changes:
//  (1) PACKED FP32: hidden chains paired into <2 x float> ext-vectors so the
//      mul/add/sub stream lowers to v_pk_mul_f32 / v_pk_add_f32 (full-rate
//      2-wide packed FP32 on gfx950). 10 instrs per chain-pair per t instead
//      of 16 -> issue floor 27 -> 17 us. Rounding of v_pk_* == scalar IEEE;
//      `#pragma clang fp contract(off)` blocks FMA contraction so spike
//      decisions stay bit-identical to the absmax-0.0 kernels.
//  (2) RH 8->4, HG 8->16, grid 2048: 8 blocks/CU = 32 waves/CU (was 16) to
//      hide the residual load/issue latency seen at VALUBusy ~75%.
// XCD swizzle: bg = blockIdx&127, hg = blockIdx>>7; hg-sharers of a bg are
// blocks == bg (mod 8) -> same XCD -> one L2 fill serves all 16.

typedef float v2f __attribute__((ext_vector_type(2)));

#define T_STEPS 128
#define BATCH   8192
#define HID     256
#define TAIL    10
#define RH      4      // hidden chains per thread (2 packed pairs)
#define NP      (RH / 2)
#define LB      64     // batch rows per block (= lanes per wave)
#define NWAVE   4      // waves per block; block covers NWAVE*RH = 16 h
#define HG      16     // h-groups (HID / 16)
#define NBG     (BATCH / LB)   // 128 batch groups
#define PF      8      // prefetch depth (t-steps in flight)

__global__ __launch_bounds__(256) void snn_scan(const float* __restrict__ x,
                                                const float* __restrict__ W1,
                                                const float* __restrict__ W2,
                                                float2* __restrict__ partial) {
#pragma clang fp contract(off)
    const int tid   = threadIdx.x;
    const int lane  = tid & 63;
    const int wave  = tid >> 6;
    const int bg    = blockIdx.x & (NBG - 1);  // same bg -> same XCD for all hg
    const int hg    = blockIdx.x >> 7;
    const int b     = bg * LB + lane;
    const int hbase = hg * (NWAVE * RH) + wave * RH;

    // W1 rows for my 4 h, packed in chain pairs (wave-uniform -> scalarized)
    v2f w0p[NP], w1p[NP];
#pragma unroll
    for (int p = 0; p < NP; ++p) {
        const int h0 = hbase + 2 * p;
        w0p[p][0] = W1[2 * h0];     w0p[p][1] = W1[2 * (h0 + 1)];
        w1p[p][0] = W1[2 * h0 + 1]; w1p[p][1] = W1[2 * (h0 + 1) + 1];
    }

    // x[t, b, 0:2] lives at xb[t * BATCH] (float2), per-lane coalesced
    const float2* xb = (const float2*)x + b;

    v2f memp[NP], spkp[NP], cntp[NP];
#pragma unroll
    for (int p = 0; p < NP; ++p) { memp[p] = (v2f)0.0f; spkp[p] = (v2f)0.0f; cntp[p] = (v2f)0.0f; }

    const v2f beta = 0.9f;   // splat

    // pk_mul, pk_mul, pk_add (cur) + pk_mul, pk_add, pk_sub (mem) + 2x(cmp,cndmask)
#define STEP(p, xav, xcv)                                                        \
    {                                                                            \
        const v2f c = ((xav) * w0p[p]) + ((xcv) * w1p[p]);                       \
        memp[p] = ((beta * memp[p]) + c) - spkp[p];                              \
        spkp[p][0] = memp[p][0] > 1.0f ? 1.0f : 0.0f;                            \
        spkp[p][1] = memp[p][1] > 1.0f ? 1.0f : 0.0f;                            \
    }

    // ---- warm-up: fill rotating prefetch buffer with t = 0..7 ----
    float2 buf[PF];
#pragma unroll
    for (int j = 0; j < PF; ++j) buf[j] = xb[(size_t)j * BATCH];

    // ---- main loop: t = 0..111, steady-state depth-8 prefetch ----
    for (int tb = 0; tb < T_STEPS - 2 * PF; tb += PF) {   // 14 iterations
#pragma unroll
        for (int j = 0; j < PF; ++j) {
            const float2 xv = buf[j];
            buf[j] = xb[(size_t)(tb + PF + j) * BATCH];   // prefetch t+8
            const v2f xav = {xv.x, xv.x};
            const v2f xcv = {xv.y, xv.y};
#pragma unroll
            for (int p = 0; p < NP; ++p) STEP(p, xav, xcv)
        }
    }

    // buf holds t = 112..119; issue loads for t = 120..127 first
    float2 buf2[PF];
#pragma unroll
    for (int j = 0; j < PF; ++j) buf2[j] = xb[(size_t)(T_STEPS - PF + j) * BATCH];

    // ---- t = 112..119 (count t = 118, 119) ----
#pragma unroll
    for (int j = 0; j < PF; ++j) {
        const float2 xv = buf[j];
        const v2f xav = {xv.x, xv.x};
        const v2f xcv = {xv.y, xv.y};
#pragma unroll
        for (int p = 0; p < NP; ++p) {
            STEP(p, xav, xcv)
            if (j >= PF - 2) cntp[p] += spkp[p];   // integer-valued, exact
        }
    }
    // ---- t = 120..127 (all counted) ----
#pragma unroll
    for (int j = 0; j < PF; ++j) {
        const float2 xv = buf2[j];
        const v2f xav = {xv.x, xv.x};
        const v2f xcv = {xv.y, xv.y};
#pragma unroll
        for (int p = 0; p < NP; ++p) {
            STEP(p, xav, xcv)
            cntp[p] += spkp[p];
        }
    }
#undef STEP

    // per-thread partial of out[b, :] over my 4 h (ascending h order)
    float p0 = 0.0f, p1 = 0.0f;
#pragma unroll
    for (int r = 0; r < RH; ++r) {
        const float cnt = cntp[r >> 1][r & 1];
        const float avg = cnt / 10.0f;
        p0 = __fadd_rn(p0, __fmul_rn(avg, W2[hbase + r]));
        p1 = __fadd_rn(p1, __fmul_rn(avg, W2[HID + hbase + r]));
    }

    // combine the block's 4 waves (different h-chunks, same b per lane)
    __shared__ float2 red[NWAVE][LB];
    red[wave][lane] = make_float2(p0, p1);
    __syncthreads();
    if (wave == 0) {
        const float2 a0 = red[0][lane], a1 = red[1][lane];
        const float2 a2 = red[2][lane], a3 = red[3][lane];
        float2 s;
        s.x = __fadd_rn(__fadd_rn(a0.x, a1.x), __fadd_rn(a2.x, a3.x));
        s.y = __fadd_rn(__fadd_rn(a0.y, a1.y), __fadd_rn(a2.y, a3.y));
        partial[(size_t)hg * BATCH + b] = s;
    }
}

// sum the 16 h-group partials -> out[b, 0:2]
__global__ __launch_bounds__(256) void snn_reduce(const float2* __restrict__ partial,
                                                  float2* __restrict__ out) {
    const int b = blockIdx.x * 256 + threadIdx.x;   // 8192 threads
    float sx = 0.0f, sy = 0.0f;
#pragma unroll
    for (int hg = 0; hg < HG; ++hg) {
        const float2 p = partial[(size_t)hg * BATCH + b];
        sx = __fadd_rn(sx, p.x);
        sy = __fadd_rn(sy, p.y);
    }
    out[b] = make_float2(sx, sy);
}

extern "C" void kernel_launch(void* const* d_in, const int* in_sizes, int n_in,
                              void* d_out, int out_size, void* d_ws, size_t ws_size,
                              hipStream_t stream) {
    const float* x  = (const float*)d_in[0];  // (128, 8192, 2)
    const float* W1 = (const float*)d_in[1];  // (256, 2)
    const float* W2 = (const float*)d_in[2];  // (2, 256)
    float2* out     = (float2*)d_out;         // (8192, 2)
    float2* partial = (float2*)d_ws;          // (16, 8192) float2 = 1 MB scratch

    snn_scan<<<NBG * HG, 256, 0, stream>>>(x, W1, W2, partial);
    snn_reduce<<<BATCH / 256, 256, 0, stream>>>(partial, out);
}

// Round 7
// 109.406 us; speedup vs baseline: 1.2761x; 1.2761x over previous
//
#include <hip/hip_runtime.h>

// SNN forward: T=128, B=8192, I=2, H=256, O=2
//  cur[t,b,h] = x[t,b,0]*W1[h,0] + x[t,b,1]*W1[h,1]
//  scan: reset = (mem>1); mem = 0.9*mem + cur - reset; spk = (mem>1)
//  out[b,o] = (mean of spk over last 10 t) dot W2[o,:]
//
// R7 = R5 structure (lane=batch, coalesced float2 x loads, XCD-correct
// swizzle, depth-8 rotating register prefetch, scalar __f*_rn math) with:
//  (1) RH 8->4 (scalar! R6's packed fp32 was a dead end: gfx950's 157 TF
//      vector peak is plain v_fma at SIMD-32; v_pk_* holds the pipe 2x
//      cycles, and the ext-vector code scalarized to VGPR=140 anyway).
//      HG 16, grid 2048 -> 8192 waves = 8 waves/SIMD (was 4): double the
//      TLP to hide the L1/L2 latency that held R5 at VALUBusy 75%.
//  (2) single rotating prefetch buffer through the tail (no buf2) +
//      __launch_bounds__(256, 8) to keep VGPR <= 64 for full occupancy.
// XCD swizzle: bg = blockIdx&127, hg = blockIdx>>7; all hg-sharers of a bg
// are == bg (mod 8) -> same XCD -> one L2 fill serves all 16.
//
// Spike-path numerics: per-op fp32 rounding (__fmul_rn/__fadd_rn/__fsub_rn,
// no FMA), identical op order to the absmax-0.0 kernels (R1/R2/R4/R5).

#define T_STEPS 128
#define BATCH   8192
#define HID     256
#define TAIL    10
#define RH      4      // hidden chains per thread
#define LB      64     // batch rows per block (= lanes per wave)
#define NWAVE   4      // waves per block; block covers NWAVE*RH = 16 h
#define HG      16     // h-groups (HID / 16)
#define NBG     (BATCH / LB)   // 128 batch groups
#define PF      8      // prefetch depth (t-steps in flight)

__global__ __launch_bounds__(256, 8) void snn_scan(const float* __restrict__ x,
                                                   const float* __restrict__ W1,
                                                   const float* __restrict__ W2,
                                                   float2* __restrict__ partial) {
    const int tid   = threadIdx.x;
    const int lane  = tid & 63;
    const int wave  = tid >> 6;
    const int bg    = blockIdx.x & (NBG - 1);  // same bg -> same XCD for all hg
    const int hg    = blockIdx.x >> 7;
    const int b     = bg * LB + lane;
    const int hbase = hg * (NWAVE * RH) + wave * RH;

    // W1 rows for my 4 h (wave-uniform addresses -> scalarized, one-time)
    float w0[RH], w1[RH];
#pragma unroll
    for (int r = 0; r < RH; ++r) {
        w0[r] = W1[2 * (hbase + r)];
        w1[r] = W1[2 * (hbase + r) + 1];
    }

    // x[t, b, 0:2] lives at xb[t * BATCH] (float2), per-lane coalesced
    const float2* xb = (const float2*)x + b;

    float mem[RH], spk[RH], cnt[RH];
#pragma unroll
    for (int r = 0; r < RH; ++r) { mem[r] = 0.0f; spk[r] = 0.0f; cnt[r] = 0.0f; }

#define STEP(r, xa, xc)                                                           \
    {                                                                             \
        const float c = __fadd_rn(__fmul_rn((xa), w0[r]), __fmul_rn((xc), w1[r]));\
        mem[r] = __fsub_rn(__fadd_rn(__fmul_rn(0.9f, mem[r]), c), spk[r]);        \
        spk[r] = (mem[r] > 1.0f) ? 1.0f : 0.0f;                                   \
    }

    // ---- warm-up: fill rotating prefetch buffer with t = 0..7 ----
    float2 buf[PF];
#pragma unroll
    for (int j = 0; j < PF; ++j) buf[j] = xb[(size_t)j * BATCH];

    // ---- main loop: t = 0..111 (14 iters), prefetch t+8 (<= 119) ----
    for (int tb = 0; tb < T_STEPS - 2 * PF; tb += PF) {
#pragma unroll
        for (int j = 0; j < PF; ++j) {
            const float2 xv = buf[j];
            buf[j] = xb[(size_t)(tb + PF + j) * BATCH];
#pragma unroll
            for (int r = 0; r < RH; ++r) STEP(r, xv.x, xv.y)
        }
    }

    // ---- t = 112..119: consume buf[j], refill with t = 120..127 ----
#pragma unroll
    for (int j = 0; j < PF; ++j) {
        const float2 xv = buf[j];
        buf[j] = xb[(size_t)(T_STEPS - PF + j) * BATCH];
#pragma unroll
        for (int r = 0; r < RH; ++r) {
            STEP(r, xv.x, xv.y)
            if (j >= PF - 2) cnt[r] += spk[r];   // t = 118, 119
        }
    }
    // ---- t = 120..127 (all counted) ----
#pragma unroll
    for (int j = 0; j < PF; ++j) {
        const float2 xv = buf[j];
#pragma unroll
        for (int r = 0; r < RH; ++r) {
            STEP(r, xv.x, xv.y)
            cnt[r] += spk[r];   // integer-valued, exact in fp32
        }
    }
#undef STEP

    // per-thread partial of out[b, :] over my 4 h (ascending h order)
    float p0 = 0.0f, p1 = 0.0f;
#pragma unroll
    for (int r = 0; r < RH; ++r) {
        const float avg = cnt[r] / 10.0f;
        p0 = __fadd_rn(p0, __fmul_rn(avg, W2[hbase + r]));
        p1 = __fadd_rn(p1, __fmul_rn(avg, W2[HID + hbase + r]));
    }

    // combine the block's 4 waves (different h-chunks, same b per lane)
    __shared__ float2 red[NWAVE][LB];
    red[wave][lane] = make_float2(p0, p1);
    __syncthreads();
    if (wave == 0) {
        const float2 a0 = red[0][lane], a1 = red[1][lane];
        const float2 a2 = red[2][lane], a3 = red[3][lane];
        float2 s;
        s.x = __fadd_rn(__fadd_rn(a0.x, a1.x), __fadd_rn(a2.x, a3.x));
        s.y = __fadd_rn(__fadd_rn(a0.y, a1.y), __fadd_rn(a2.y, a3.y));
        partial[(size_t)hg * BATCH + b] = s;
    }
}

// sum the 16 h-group partials -> out[b, 0:2]
__global__ __launch_bounds__(256) void snn_reduce(const float2* __restrict__ partial,
                                                  float2* __restrict__ out) {
    const int b = blockIdx.x * 256 + threadIdx.x;   // 8192 threads
    float sx = 0.0f, sy = 0.0f;
#pragma unroll
    for (int hg = 0; hg < HG; ++hg) {
        const float2 p = partial[(size_t)hg * BATCH + b];
        sx = __fadd_rn(sx, p.x);
        sy = __fadd_rn(sy, p.y);
    }
    out[b] = make_float2(sx, sy);
}

extern "C" void kernel_launch(void* const* d_in, const int* in_sizes, int n_in,
                              void* d_out, int out_size, void* d_ws, size_t ws_size,
                              hipStream_t stream) {
    const float* x  = (const float*)d_in[0];  // (128, 8192, 2)
    const float* W1 = (const float*)d_in[1];  // (256, 2)
    const float* W2 = (const float*)d_in[2];  // (2, 256)
    float2* out     = (float2*)d_out;         // (8192, 2)
    float2* partial = (float2*)d_ws;          // (16, 8192) float2 = 1 MB scratch

    snn_scan<<<NBG * HG, 256, 0, stream>>>(x, W1, W2, partial);
    snn_reduce<<<BATCH / 256, 256, 0, stream>>>(partial, out);
}

// Round 8
// 104.722 us; speedup vs baseline: 1.3331x; 1.0447x over previous
//
#include <hip/hip_runtime.h>

// SNN forward: T=128, B=8192, I=2, H=256, O=2
//  cur[t,b,h] = x[t,b,0]*W1[h,0] + x[t,b,1]*W1[h,1]
//  scan: reset = (mem>1); mem = 0.9*mem + cur - reset; spk = (mem>1)
//  out[b,o] = (mean of spk over last 10 t) dot W2[o,:]
//
// R8 = R7 minus the two things that hurt it:
//  (1) NO waves-per-EU clamp. R7's __launch_bounds__(256,8) made the compiler
//      squeeze to VGPR=32 and spill (WRITE_SIZE 0.5->17.4 MB of scratch).
//      RH=4 needs ~45-50 VGPR naturally (<=64), so 32 waves/CU is reachable
//      without any clamp.
//  (2) saddr-form addressing: loads written as xt[b] with a UNIFORM t-offset
//      (x + t*BATCH uniform SGPR base, b*8 fixed 32-bit VGPR voffset) instead
//      of R5/R7's lane-dependent base + 64-bit offset, which cost v_add_co/
//      v_addc per load inside the hot loop (~40% VALU overhead over the
//      27.3 us chain floor).
// Kept: lane=batch, coalesced float2 loads, XCD swizzle (bg=blockIdx&127,
// hg=blockIdx>>7: all hg-sharers of one x-slice land on XCD bg%8), depth-8
// rotating register prefetch, two-kernel h-partial reduction.
//
// Spike-path numerics: per-op fp32 rounding (__fmul_rn/__fadd_rn/__fsub_rn,
// no FMA), identical op order to the absmax-0.0 kernels (R1/R2/R4/R5/R7).

#define T_STEPS 128
#define BATCH   8192
#define HID     256
#define TAIL    10
#define RH      4      // hidden chains per thread
#define LB      64     // batch rows per block (= lanes per wave)
#define NWAVE   4      // waves per block; block covers NWAVE*RH = 16 h
#define HG      16     // h-groups (HID / 16)
#define NBG     (BATCH / LB)   // 128 batch groups
#define PF      8      // prefetch depth (t-steps in flight)

__global__ __launch_bounds__(256) void snn_scan(const float* __restrict__ x,
                                                const float* __restrict__ W1,
                                                const float* __restrict__ W2,
                                                float2* __restrict__ partial) {
    const int tid   = threadIdx.x;
    const int lane  = tid & 63;
    const int wave  = tid >> 6;
    const int bg    = blockIdx.x & (NBG - 1);  // same bg -> same XCD for all hg
    const int hg    = blockIdx.x >> 7;
    const int b     = bg * LB + lane;          // batch row (lane part of addr)
    const int hbase = hg * (NWAVE * RH) + wave * RH;

    // W1 rows for my 4 h (wave-uniform addresses -> scalarized, one-time)
    float w0[RH], w1[RH];
#pragma unroll
    for (int r = 0; r < RH; ++r) {
        w0[r] = W1[2 * (hbase + r)];
        w1[r] = W1[2 * (hbase + r) + 1];
    }

    // Uniform-base addressing: xp + t*BATCH is wave-uniform (SGPR base,
    // stepped by SALU); + b is the fixed per-lane voffset.
    const float2* xp = (const float2*)x;

    float mem[RH], spk[RH], cnt[RH];
#pragma unroll
    for (int r = 0; r < RH; ++r) { mem[r] = 0.0f; spk[r] = 0.0f; cnt[r] = 0.0f; }

#define LOADX(t) xp[(size_t)(t) * BATCH + b]

#define STEP(r, xa, xc)                                                           \
    {                                                                             \
        const float c = __fadd_rn(__fmul_rn((xa), w0[r]), __fmul_rn((xc), w1[r]));\
        mem[r] = __fsub_rn(__fadd_rn(__fmul_rn(0.9f, mem[r]), c), spk[r]);        \
        spk[r] = (mem[r] > 1.0f) ? 1.0f : 0.0f;                                   \
    }

    // ---- warm-up: fill rotating prefetch buffer with t = 0..7 ----
    float2 buf[PF];
#pragma unroll
    for (int j = 0; j < PF; ++j) buf[j] = LOADX(j);

    // ---- main loop: t = 0..111 (14 iters), prefetch t+8 (<= 119) ----
    for (int tb = 0; tb < T_STEPS - 2 * PF; tb += PF) {
#pragma unroll
        for (int j = 0; j < PF; ++j) {
            const float2 xv = buf[j];
            buf[j] = LOADX(tb + PF + j);
#pragma unroll
            for (int r = 0; r < RH; ++r) STEP(r, xv.x, xv.y)
        }
    }

    // ---- t = 112..119: consume buf[j], refill with t = 120..127 ----
#pragma unroll
    for (int j = 0; j < PF; ++j) {
        const float2 xv = buf[j];
        buf[j] = LOADX(T_STEPS - PF + j);
#pragma unroll
        for (int r = 0; r < RH; ++r) {
            STEP(r, xv.x, xv.y)
            if (j >= PF - 2) cnt[r] += spk[r];   // t = 118, 119
        }
    }
    // ---- t = 120..127 (all counted) ----
#pragma unroll
    for (int j = 0; j < PF; ++j) {
        const float2 xv = buf[j];
#pragma unroll
        for (int r = 0; r < RH; ++r) {
            STEP(r, xv.x, xv.y)
            cnt[r] += spk[r];   // integer-valued, exact in fp32
        }
    }
#undef STEP
#undef LOADX

    // per-thread partial of out[b, :] over my 4 h (ascending h order)
    float p0 = 0.0f, p1 = 0.0f;
#pragma unroll
    for (int r = 0; r < RH; ++r) {
        const float avg = cnt[r] / 10.0f;
        p0 = __fadd_rn(p0, __fmul_rn(avg, W2[hbase + r]));
        p1 = __fadd_rn(p1, __fmul_rn(avg, W2[HID + hbase + r]));
    }

    // combine the block's 4 waves (different h-chunks, same b per lane)
    __shared__ float2 red[NWAVE][LB];
    red[wave][lane] = make_float2(p0, p1);
    __syncthreads();
    if (wave == 0) {
        const float2 a0 = red[0][lane], a1 = red[1][lane];
        const float2 a2 = red[2][lane], a3 = red[3][lane];
        float2 s;
        s.x = __fadd_rn(__fadd_rn(a0.x, a1.x), __fadd_rn(a2.x, a3.x));
        s.y = __fadd_rn(__fadd_rn(a0.y, a1.y), __fadd_rn(a2.y, a3.y));
        partial[(size_t)hg * BATCH + b] = s;
    }
}

// sum the 16 h-group partials -> out[b, 0:2]
__global__ __launch_bounds__(256) void snn_reduce(const float2* __restrict__ partial,
                                                  float2* __restrict__ out) {
    const int b = blockIdx.x * 256 + threadIdx.x;   // 8192 threads
    float sx = 0.0f, sy = 0.0f;
#pragma unroll
    for (int hg = 0; hg < HG; ++hg) {
        const float2 p = partial[(size_t)hg * BATCH + b];
        sx = __fadd_rn(sx, p.x);
        sy = __fadd_rn(sy, p.y);
    }
    out[b] = make_float2(sx, sy);
}

extern "C" void kernel_launch(void* const* d_in, const int* in_sizes, int n_in,
                              void* d_out, int out_size, void* d_ws, size_t ws_size,
                              hipStream_t stream) {
    const float* x  = (const float*)d_in[0];  // (128, 8192, 2)
    const float* W1 = (const float*)d_in[1];  // (256, 2)
    const float* W2 = (const float*)d_in[2];  // (2, 256)
    float2* out     = (float2*)d_out;         // (8192, 2)
    float2* partial = (float2*)d_ws;          // (16, 8192) float2 = 1 MB scratch

    snn_scan<<<NBG * HG, 256, 0, stream>>>(x, W1, W2, partial);
    snn_reduce<<<BATCH / 256, 256, 0, stream>>>(partial, out);
}